// Round 1
// baseline (761.931 us; speedup 1.0000x reference)
//
#include <hip/hip_runtime.h>
#include <math.h>

// ---------------------------------------------------------------------------
// Problem constants (from reference):
//   B=16, N=1024, C=256, SIZE=(512,640), STRIDE=8 -> H0=64, W0=80, P_TOK=5120
//   NHEAD=8, NLVL=4, NPTS=4, HD=32, NUM_CLASSES=7
//   pyramid shapes: (64,80) (32,40) (16,20) (8,10); S_total = 6800
// ---------------------------------------------------------------------------

namespace {

constexpr int kB = 16;
constexpr int kN = 1024;
constexpr int kC = 256;
constexpr int kNH = 8;
constexpr int kHD = 32;
constexpr int kNCLS = 7;
constexpr int kSTOT = 6800;

// workspace layout (float offsets)
constexpr size_t kLvl2Off = 5242880;    // 16*1280*256
constexpr size_t kLvl3Off = 6553600;    // + 16*320*256
constexpr size_t kLvlTot  = 6881280;    // + 16*80*256
constexpr size_t kValueOff = kLvlTot;                    // 27,852,800 floats
constexpr size_t kOffOff   = kValueOff + 27852800;       // 4,194,304
constexpr size_t kAttnOff  = kOffOff + 4194304;          // 2,097,152
constexpr size_t kSampOff  = kAttnOff + 2097152;         // 4,194,304
constexpr size_t kQlocOff  = kSampOff + 4194304;         // 4,194,304
// aliases (lvl+value dead by the time these are written):
constexpr size_t kQfusOff  = 0;                          // 8,388,608
constexpr size_t kHidOff   = 8388608;                    // 4,194,304

// ---------------- 2x2 average pool: (B,2h,2w,C) -> (B,h,w,C) ----------------
__global__ void pool2x2_kernel(const float* __restrict__ in, float* __restrict__ out,
                               int oh, int ow) {
  int idx = blockIdx.x * 256 + threadIdx.x;
  int total = kB * oh * ow * kC;
  if (idx >= total) return;
  int c = idx & 255;
  int t = idx >> 8;
  int x = t % ow; t /= ow;
  int y = t % oh; t /= oh;
  int b = t;
  int iw = ow * 2;
  const float* p = in + ((((size_t)b * (oh * 2) + 2 * y) * iw + 2 * x) << 8) + c;
  size_t rs = (size_t)iw << 8;
  out[idx] = 0.25f * (p[0] + p[kC] + p[rs] + p[rs + kC]);
}

// ---------------- generic fp32 GEMM: C[M,NC] = A[M,KTOT] @ W[KTOT,NC] + bias -
// 64x64 output tile per block (256 threads), K-step 16.
// AMODE 0: A rows contiguous from A0 (stride KTOT).
// AMODE 1: pyramid rows: level0 from A0 (h_t), levels 1..3 from A1 (pooled).
template <int KTOT, int NC, int AMODE, bool RELU>
__global__ __launch_bounds__(256) void gemm_f32_kernel(
    const float* __restrict__ A0, const float* __restrict__ A1,
    const float* __restrict__ W, const float* __restrict__ bias,
    float* __restrict__ Cout) {
  __shared__ float As[16][64];
  __shared__ float Bs[16][64];
  const int tid = threadIdx.x;
  const int bm = blockIdx.y << 6;
  const int bn = blockIdx.x << 6;

  // A staging: thread loads float4 of row (bm + tid/4), k-quad (tid%4)*4
  const int lm = tid >> 2;
  const int lk = (tid & 3) << 2;
  const int row = bm + lm;
  const float* arow;
  if (AMODE == 1) {
    int b = row / kSTOT;
    int s = row - b * kSTOT;
    if (s < 5120)      arow = A0 + (((size_t)b * 5120 + s) << 8);
    else if (s < 6400) arow = A1 + (((size_t)b * 1280 + (s - 5120)) << 8);
    else if (s < 6720) arow = A1 + kLvl2Off + (((size_t)b * 320 + (s - 6400)) << 8);
    else               arow = A1 + kLvl3Off + (((size_t)b * 80 + (s - 6720)) << 8);
  } else {
    arow = A0 + (size_t)row * KTOT;
  }
  // B staging: thread loads float4 of W row (tid/16), col-quad (tid%16)*4
  const int bk = tid >> 4;
  const int bn4 = (tid & 15) << 2;
  const float* wp = W + (size_t)bk * NC + bn + bn4;

  const int m0 = (tid >> 4) << 2;
  const int n0 = (tid & 15) << 2;

  float acc[4][4];
#pragma unroll
  for (int i = 0; i < 4; ++i)
#pragma unroll
    for (int j = 0; j < 4; ++j) acc[i][j] = 0.f;

  for (int k0 = 0; k0 < KTOT; k0 += 16) {
    float4 av = *(const float4*)(arow + k0 + lk);
    float4 bv = *(const float4*)(wp + (size_t)k0 * NC);
    As[lk + 0][lm] = av.x;
    As[lk + 1][lm] = av.y;
    As[lk + 2][lm] = av.z;
    As[lk + 3][lm] = av.w;
    *(float4*)&Bs[bk][bn4] = bv;
    __syncthreads();
#pragma unroll
    for (int kk = 0; kk < 16; ++kk) {
      float4 a4 = *(const float4*)&As[kk][m0];
      float4 b4 = *(const float4*)&Bs[kk][n0];
      float a[4] = {a4.x, a4.y, a4.z, a4.w};
      float b[4] = {b4.x, b4.y, b4.z, b4.w};
#pragma unroll
      for (int i = 0; i < 4; ++i)
#pragma unroll
        for (int j = 0; j < 4; ++j) acc[i][j] = fmaf(a[i], b[j], acc[i][j]);
    }
    __syncthreads();
  }

  float4 bias4 = *(const float4*)(bias + bn + n0);
  float bvals[4] = {bias4.x, bias4.y, bias4.z, bias4.w};
#pragma unroll
  for (int i = 0; i < 4; ++i) {
    float o[4];
#pragma unroll
    for (int j = 0; j < 4; ++j) {
      o[j] = acc[i][j] + bvals[j];
      if (RELU) o[j] = fmaxf(o[j], 0.f);
    }
    float4 ov = {o[0], o[1], o[2], o[3]};
    *(float4*)&Cout[(size_t)(bm + m0 + i) * NC + bn + n0] = ov;
  }
}

// ---------------- softmax over rows of 16 (in place) ------------------------
__global__ void softmax16_kernel(float* __restrict__ att, int rows) {
  int r = blockIdx.x * 256 + threadIdx.x;
  if (r >= rows) return;
  float4* p = (float4*)(att + ((size_t)r << 4));
  float4 v0 = p[0], v1 = p[1], v2 = p[2], v3 = p[3];
  float x[16] = {v0.x, v0.y, v0.z, v0.w, v1.x, v1.y, v1.z, v1.w,
                 v2.x, v2.y, v2.z, v2.w, v3.x, v3.y, v3.z, v3.w};
  float m = x[0];
#pragma unroll
  for (int i = 1; i < 16; ++i) m = fmaxf(m, x[i]);
  float s = 0.f;
#pragma unroll
  for (int i = 0; i < 16; ++i) {
    x[i] = expf(x[i] - m);
    s += x[i];
  }
  float inv = 1.f / s;
#pragma unroll
  for (int i = 0; i < 16; ++i) x[i] *= inv;
  p[0] = make_float4(x[0], x[1], x[2], x[3]);
  p[1] = make_float4(x[4], x[5], x[6], x[7]);
  p[2] = make_float4(x[8], x[9], x[10], x[11]);
  p[3] = make_float4(x[12], x[13], x[14], x[15]);
}

// ---------------- deformable bilinear sampling ------------------------------
// thread t = (((b*N + n)*NH + h)*HD + d); out layout (B,N,NH*HD) = (B,N,C)
__global__ void deform_sample_kernel(const float* __restrict__ value,
                                     const float* __restrict__ off,
                                     const float* __restrict__ attn,
                                     const float* __restrict__ p_head,
                                     float* __restrict__ outp) {
  int t = blockIdx.x * 256 + threadIdx.x;
  int d = t & 31;
  int h = (t >> 5) & 7;
  int n = (t >> 8) & 1023;
  int b = t >> 18;

  float px = p_head[((((size_t)b << 10) + n) << 1) + 0] * (1.0f / 640.0f);
  float py = p_head[((((size_t)b << 10) + n) << 1) + 1] * (1.0f / 512.0f);
  px = fminf(fmaxf(px, 0.f), 1.f);
  py = fminf(fmaxf(py, 0.f), 1.f);

  const float* offr = off + ((((size_t)b << 10) + n) << 8) + (h << 5);   // (nh,4,4,2)
  const float* attr = attn + ((((size_t)b << 10) + n) << 7) + (h << 4);  // (nh,16)

  const int lvlW[4] = {80, 40, 20, 10};
  const int lvlH[4] = {64, 32, 16, 8};
  const int lvlO[4] = {0, 5120, 6400, 6720};

  float acc = 0.f;
#pragma unroll
  for (int l = 0; l < 4; ++l) {
    const int Wl = lvlW[l], Hl = lvlH[l];
    const float* vbase = value + (((size_t)b * kSTOT + lvlO[l]) << 8) + (h << 5) + d;
    const float fx = px * (float)Wl, fy = py * (float)Hl;
#pragma unroll
    for (int p = 0; p < 4; ++p) {
      float ox = offr[(((l << 2) + p) << 1) + 0];
      float oy = offr[(((l << 2) + p) << 1) + 1];
      float aw = attr[(l << 2) + p];
      float xx = fx + ox - 0.5f;
      float yy = fy + oy - 0.5f;
      float x0f = floorf(xx), y0f = floorf(yy);
      float wx = xx - x0f, wy = yy - y0f;
      int x0 = (int)x0f, y0 = (int)y0f;
      float s = 0.f;
#pragma unroll
      for (int cy = 0; cy < 2; ++cy) {
#pragma unroll
        for (int cx = 0; cx < 2; ++cx) {
          int xi = x0 + cx, yi = y0 + cy;
          float w = (cx ? wx : 1.f - wx) * (cy ? wy : 1.f - wy);
          bool valid = (xi >= 0) && (xi < Wl) && (yi >= 0) && (yi < Hl);
          int xc = xi < 0 ? 0 : (xi > Wl - 1 ? Wl - 1 : xi);
          int yc = yi < 0 ? 0 : (yi > Hl - 1 ? Hl - 1 : yi);
          float v = vbase[(size_t)(yc * Wl + xc) << 8];
          s = fmaf(valid ? w : 0.f, v, s);
        }
      }
      acc = fmaf(aw, s, acc);
    }
  }
  outp[t] = acc;
}

// ---------------- concat q_t (256) with q_local (256) -> 512 ----------------
__global__ void concat_kernel(const float* __restrict__ qt, const float* __restrict__ ql,
                              float* __restrict__ qf) {
  int i = blockIdx.x * 256 + threadIdx.x;  // over B*N*128 float4s
  if (i >= kB * kN * 128) return;
  int c4 = i & 127;
  size_t r = (size_t)(i >> 7);
  float4 v;
  if (c4 < 64)
    v = ((const float4*)qt)[(r << 6) + c4];
  else
    v = ((const float4*)ql)[(r << 6) + (c4 - 64)];
  ((float4*)qf)[i] = v;
}

// ---------------- final head: (B*N,256)@(256,7)+b, one wave per row ---------
__global__ void head_kernel(const float* __restrict__ hid, const float* __restrict__ W2,
                            const float* __restrict__ b2, float* __restrict__ outp) {
  int gid = blockIdx.x * 256 + threadIdx.x;
  int wave = gid >> 6;
  int lane = threadIdx.x & 63;
  if (wave >= kB * kN) return;
  const float* hrow = hid + ((size_t)wave << 8);
  float acc[kNCLS];
#pragma unroll
  for (int j = 0; j < kNCLS; ++j) acc[j] = 0.f;
  for (int k = lane; k < kC; k += 64) {
    float hv = hrow[k];
    const float* wr = W2 + k * kNCLS;
#pragma unroll
    for (int j = 0; j < kNCLS; ++j) acc[j] = fmaf(hv, wr[j], acc[j]);
  }
#pragma unroll
  for (int m = 32; m > 0; m >>= 1) {
#pragma unroll
    for (int j = 0; j < kNCLS; ++j) acc[j] += __shfl_xor(acc[j], m);
  }
  float r = 0.f;
#pragma unroll
  for (int j = 0; j < kNCLS; ++j)
    if (lane == j) r = acc[j] + b2[j];
  if (lane < kNCLS) outp[(size_t)wave * kNCLS + lane] = r;
}

}  // namespace

extern "C" void kernel_launch(void* const* d_in, const int* in_sizes, int n_in,
                              void* d_out, int out_size, void* d_ws, size_t ws_size,
                              hipStream_t stream) {
  const float* q_t    = (const float*)d_in[0];
  const float* h_t    = (const float*)d_in[1];
  const float* p_head = (const float*)d_in[2];
  const float* W_off  = (const float*)d_in[3];
  const float* b_off  = (const float*)d_in[4];
  const float* W_attn = (const float*)d_in[5];
  const float* b_attn = (const float*)d_in[6];
  const float* W_v    = (const float*)d_in[7];
  const float* b_v    = (const float*)d_in[8];
  const float* W_o    = (const float*)d_in[9];
  const float* b_o    = (const float*)d_in[10];
  const float* W_p1   = (const float*)d_in[11];
  const float* b_p1   = (const float*)d_in[12];
  const float* W_p2   = (const float*)d_in[13];
  const float* b_p2   = (const float*)d_in[14];
  float* out = (float*)d_out;
  float* ws = (float*)d_ws;

  float* lvl   = ws;             // pooled levels 1..3
  float* value = ws + kValueOff;
  float* offb  = ws + kOffOff;
  float* attn  = ws + kAttnOff;
  float* samp  = ws + kSampOff;
  float* qloc  = ws + kQlocOff;
  float* qfus  = ws + kQfusOff;  // aliases lvl+value head (dead by then)
  float* hid   = ws + kHidOff;   // aliases value region (dead by then)

  // 1) feature pyramid by 2x2 average pooling
  pool2x2_kernel<<<(kB * 32 * 40 * kC + 255) / 256, 256, 0, stream>>>(h_t, lvl, 32, 40);
  pool2x2_kernel<<<(kB * 16 * 20 * kC + 255) / 256, 256, 0, stream>>>(lvl, lvl + kLvl2Off, 16, 20);
  pool2x2_kernel<<<(kB * 8 * 10 * kC + 255) / 256, 256, 0, stream>>>(lvl + kLvl2Off, lvl + kLvl3Off, 8, 10);

  // 2) value = f_scales @ W_v + b_v   (M = 16*6800 = 108800)
  gemm_f32_kernel<256, 256, 1, false><<<dim3(4, 1700), 256, 0, stream>>>(
      h_t, lvl, W_v, b_v, value);

  // 3) offsets = q_t @ W_off + b_off  (M = 16384)
  gemm_f32_kernel<256, 256, 0, false><<<dim3(4, 256), 256, 0, stream>>>(
      q_t, nullptr, W_off, b_off, offb);

  // 4) attn logits = q_t @ W_attn + b_attn
  gemm_f32_kernel<256, 128, 0, false><<<dim3(2, 256), 256, 0, stream>>>(
      q_t, nullptr, W_attn, b_attn, attn);

  // 5) softmax over 16 per (b,n,head)
  softmax16_kernel<<<(kB * kN * kNH + 255) / 256, 256, 0, stream>>>(attn, kB * kN * kNH);

  // 6) deformable bilinear sampling -> samp (B,N,C)
  deform_sample_kernel<<<(kB * kN * kNH * kHD) / 256, 256, 0, stream>>>(
      value, offb, attn, p_head, samp);

  // 7) q_local = samp @ W_o + b_o
  gemm_f32_kernel<256, 256, 0, false><<<dim3(4, 256), 256, 0, stream>>>(
      samp, nullptr, W_o, b_o, qloc);

  // 8) q_fused = concat(q_t, q_local)
  concat_kernel<<<(kB * kN * 128 + 255) / 256, 256, 0, stream>>>(q_t, qloc, qfus);

  // 9) hid = relu(q_fused @ W_p1 + b_p1)
  gemm_f32_kernel<512, 256, 0, true><<<dim3(4, 256), 256, 0, stream>>>(
      qfus, nullptr, W_p1, b_p1, hid);

  // 10) logits = hid @ W_p2 + b_p2
  head_kernel<<<(kB * kN * 64 + 255) / 256, 256, 0, stream>>>(hid, W_p2, b_p2, out);
}

// Round 2
// 256.943 us; speedup vs baseline: 2.9654x; 2.9654x over previous
//
#include <hip/hip_runtime.h>
#include <math.h>

// ---------------------------------------------------------------------------
// B=16, N=1024, C=256, SIZE=(512,640), STRIDE=8 -> H0=64, W0=80, P_TOK=5120
// NHEAD=8, NLVL=4, NPTS=4, HD=32, NUM_CLASSES=7
// pyramid: (64,80)(32,40)(16,20)(8,10); S_total=6800
// ---------------------------------------------------------------------------

namespace {

constexpr int kB = 16;
constexpr int kN = 1024;
constexpr int kC = 256;
constexpr int kNCLS = 7;
constexpr int kSTOT = 6800;

typedef __attribute__((ext_vector_type(8))) short short8;
typedef __attribute__((ext_vector_type(4))) float f32x4;

__device__ inline ushort f2bf(float f) {
  union { float f; unsigned u; } v; v.f = f;
  unsigned r = (v.u + 0x7fffu + ((v.u >> 16) & 1u)) >> 16;
  return (ushort)r;
}
__device__ inline float bf2f(ushort h) {
  union { unsigned u; float f; } v; v.u = ((unsigned)h) << 16;
  return v.f;
}

__device__ inline void gload16(const ushort* g, ushort* l) {
  __builtin_amdgcn_global_load_lds(
      (const __attribute__((address_space(1))) void*)g,
      (__attribute__((address_space(3))) void*)l, 16, 0, 0);
}

// ---------------- elementwise casts ----------------------------------------
__global__ void cast_f2b_kernel(const float* __restrict__ in, ushort* __restrict__ out, int n4) {
  int i = blockIdx.x * 256 + threadIdx.x;
  if (i >= n4) return;
  float4 v = ((const float4*)in)[i];
  ((ushort4*)out)[i] = make_ushort4(f2bf(v.x), f2bf(v.y), f2bf(v.z), f2bf(v.w));
}

// h_t (b,5120,256) fp32 -> fsc rows (b*6800+s) bf16
__global__ void cast_h_kernel(const float* __restrict__ h, ushort* __restrict__ fsc) {
  int i = blockIdx.x * 256 + threadIdx.x;  // over 16*5120*64 quads
  if (i >= kB * 5120 * 64) return;
  int q = i & 63;
  int t = i >> 6;
  int s = t % 5120, b = t / 5120;
  float4 v = ((const float4*)h)[i];
  ((ushort4*)fsc)[((size_t)b * kSTOT + s) * 64 + q] =
      make_ushort4(f2bf(v.x), f2bf(v.y), f2bf(v.z), f2bf(v.w));
}

// level0 fp32 -> level1 bf16 (into fsc at S-offset 5120)
__global__ void pool_f2b_kernel(const float* __restrict__ in, ushort* __restrict__ fsc) {
  int idx = blockIdx.x * 256 + threadIdx.x;
  if (idx >= kB * 32 * 40 * kC) return;
  int c = idx & 255; int t = idx >> 8;
  int x = t % 40; t /= 40; int y = t % 32; int b = t / 32;
  const float* p = in + (((size_t)b * 5120 + y * 2 * 80 + x * 2) << 8) + c;
  float s = 0.25f * (p[0] + p[256] + p[80 * 256] + p[80 * 256 + 256]);
  fsc[(((size_t)b * kSTOT + 5120 + y * 40 + x) << 8) + c] = f2bf(s);
}

__global__ void pool_b2b_kernel(const ushort* __restrict__ fin, ushort* __restrict__ fout,
                                int oh, int ow, int so_in, int so_out) {
  int idx = blockIdx.x * 256 + threadIdx.x;
  if (idx >= kB * oh * ow * kC) return;
  int c = idx & 255; int t = idx >> 8;
  int x = t % ow; t /= ow; int y = t % oh; int b = t / oh;
  int iw = ow * 2;
  const ushort* p = fin + (((size_t)b * kSTOT + so_in + y * 2 * iw + x * 2) << 8) + c;
  float s = 0.25f * (bf2f(p[0]) + bf2f(p[256]) + bf2f(p[iw * 256]) + bf2f(p[iw * 256 + 256]));
  fout[(((size_t)b * kSTOT + so_out + y * ow + x) << 8) + c] = f2bf(s);
}

// W [K][N] fp32 -> Wt [N][K] bf16
__global__ void wtrans_kernel(const float* __restrict__ W, ushort* __restrict__ Wt, int K, int N) {
  __shared__ float t[32][33];
  int nx = blockIdx.x << 5, ky = blockIdx.y << 5;
  int lx = threadIdx.x & 31, ly = threadIdx.x >> 5;
#pragma unroll
  for (int i = 0; i < 32; i += 8)
    t[ly + i][lx] = W[(size_t)(ky + ly + i) * N + nx + lx];
  __syncthreads();
#pragma unroll
  for (int i = 0; i < 32; i += 8)
    Wt[(size_t)(nx + ly + i) * K + ky + lx] = f2bf(t[lx][ly + i]);
}

// ---------------- bf16 MFMA GEMM: C[M,NC] = A[M,K] @ Wt[NC,K]^T + bias ------
// 128x128 tile, 4 waves, BK=32. A,Wt bf16; out fp32 or bf16.
// LDS granule swizzle s(row)=(row>>1)&3 applied on global source AND ds_read.
template <int KTOT, bool RELU, bool OUTBF>
__global__ __launch_bounds__(256) void gemm_bf16_kernel(
    const ushort* __restrict__ A, const ushort* __restrict__ Wt,
    const float* __restrict__ bias, void* __restrict__ Cout, int ldc) {
  __shared__ ushort Asm[128 * 32];
  __shared__ ushort Bsm[128 * 32];
  const int tid = threadIdx.x;
  const int w = tid >> 6, l = tid & 63;
  const int bm = blockIdx.y << 7, bn = blockIdx.x << 7;
  const int wm = w >> 1, wn = w & 1;

  // staging: chunk c covers LDS granules [c*64, c*64+64), granule G -> row G>>2, g G&3
  const int c0 = w * 2, c1 = w * 2 + 1;
  const int G0 = c0 * 64 + l, G1 = c1 * 64 + l;
  const int r0 = G0 >> 2, g0 = G0 & 3;
  const int r1 = G1 >> 2, g1 = G1 & 3;
  const ushort* srcA0 = A + (size_t)(bm + r0) * KTOT + ((g0 ^ ((r0 >> 1) & 3)) << 3);
  const ushort* srcA1 = A + (size_t)(bm + r1) * KTOT + ((g1 ^ ((r1 >> 1) & 3)) << 3);
  const ushort* srcB0 = Wt + (size_t)(bn + r0) * KTOT + ((g0 ^ ((r0 >> 1) & 3)) << 3);
  const ushort* srcB1 = Wt + (size_t)(bn + r1) * KTOT + ((g1 ^ ((r1 >> 1) & 3)) << 3);
  ushort* ldsA0 = Asm + c0 * 512;  // wave-uniform bases
  ushort* ldsA1 = Asm + c1 * 512;
  ushort* ldsB0 = Bsm + c0 * 512;
  ushort* ldsB1 = Bsm + c1 * 512;

  // fragment read offsets (elems), swizzled
  const int e = l >> 4, rl = l & 15;
  int aoff[4], boff[4];
#pragma unroll
  for (int i = 0; i < 4; ++i) {
    int r = wm * 64 + i * 16 + rl;
    aoff[i] = r * 32 + ((e ^ ((r >> 1) & 3)) << 3);
    int rb = wn * 64 + i * 16 + rl;
    boff[i] = rb * 32 + ((e ^ ((rb >> 1) & 3)) << 3);
  }

  f32x4 acc[4][4];
#pragma unroll
  for (int i = 0; i < 4; ++i)
#pragma unroll
    for (int j = 0; j < 4; ++j) acc[i][j] = (f32x4){0.f, 0.f, 0.f, 0.f};

  for (int k0 = 0; k0 < KTOT; k0 += 32) {
    if (k0) __syncthreads();
    gload16(srcA0 + k0, ldsA0);
    gload16(srcA1 + k0, ldsA1);
    gload16(srcB0 + k0, ldsB0);
    gload16(srcB1 + k0, ldsB1);
    __syncthreads();  // drains vmcnt before barrier -> LDS ready
    short8 af[4], bf[4];
#pragma unroll
    for (int i = 0; i < 4; ++i) af[i] = *(const short8*)&Asm[aoff[i]];
#pragma unroll
    for (int j = 0; j < 4; ++j) bf[j] = *(const short8*)&Bsm[boff[j]];
#pragma unroll
    for (int i = 0; i < 4; ++i)
#pragma unroll
      for (int j = 0; j < 4; ++j)
        acc[i][j] = __builtin_amdgcn_mfma_f32_16x16x32_bf16(af[i], bf[j], acc[i][j], 0, 0, 0);
  }

  // epilogue: C/D layout col=lane&15, row=(lane>>4)*4+reg  [m89-verified]
#pragma unroll
  for (int j = 0; j < 4; ++j) {
    int col = bn + wn * 64 + j * 16 + rl;
    float bj = bias[col];
#pragma unroll
    for (int i = 0; i < 4; ++i) {
      int rbase = bm + wm * 64 + i * 16 + e * 4;
#pragma unroll
      for (int r = 0; r < 4; ++r) {
        float v = acc[i][j][r] + bj;
        if (RELU) v = fmaxf(v, 0.f);
        if (OUTBF)
          ((ushort*)Cout)[(size_t)(rbase + r) * ldc + col] = f2bf(v);
        else
          ((float*)Cout)[(size_t)(rbase + r) * ldc + col] = v;
      }
    }
  }
}

// ---------------- softmax over rows of 16 (in place, fp32) ------------------
__global__ void softmax16_kernel(float* __restrict__ att, int rows) {
  int r = blockIdx.x * 256 + threadIdx.x;
  if (r >= rows) return;
  float4* p = (float4*)(att + ((size_t)r << 4));
  float4 v0 = p[0], v1 = p[1], v2 = p[2], v3 = p[3];
  float x[16] = {v0.x, v0.y, v0.z, v0.w, v1.x, v1.y, v1.z, v1.w,
                 v2.x, v2.y, v2.z, v2.w, v3.x, v3.y, v3.z, v3.w};
  float m = x[0];
#pragma unroll
  for (int i = 1; i < 16; ++i) m = fmaxf(m, x[i]);
  float s = 0.f;
#pragma unroll
  for (int i = 0; i < 16; ++i) { x[i] = expf(x[i] - m); s += x[i]; }
  float inv = 1.f / s;
#pragma unroll
  for (int i = 0; i < 16; ++i) x[i] *= inv;
  p[0] = make_float4(x[0], x[1], x[2], x[3]);
  p[1] = make_float4(x[4], x[5], x[6], x[7]);
  p[2] = make_float4(x[8], x[9], x[10], x[11]);
  p[3] = make_float4(x[12], x[13], x[14], x[15]);
}

// ---------------- deformable sampling: one wave per (b,n) -------------------
// lane = h*8 + dq ; thread computes d = dq*4..dq*4+3 (ushort4 gathers of bf16 value)
__global__ __launch_bounds__(256) void deform_kernel(
    const ushort* __restrict__ value, const float* __restrict__ off,
    const float* __restrict__ attn, const float* __restrict__ p_head,
    ushort* __restrict__ samp) {
  int blk = (int)blockIdx.x;
  int sw = (blk & 7) * 512 + (blk >> 3);  // bijective XCD-chunk swizzle (4096 = 8*512)
  int wv = (sw << 2) + (threadIdx.x >> 6);
  int l = threadIdx.x & 63;
  int h = l >> 3, dq = l & 7;
  int b = wv >> 10;
  size_t bn = (size_t)wv;

  float ph = (l < 2) ? p_head[bn * 2 + l] : 0.f;
  float px = __shfl(ph, 0, 64) * (1.0f / 640.0f);
  float py = __shfl(ph, 1, 64) * (1.0f / 512.0f);
  px = fminf(fmaxf(px, 0.f), 1.f);
  py = fminf(fmaxf(py, 0.f), 1.f);

  float4 ofv = ((const float4*)(off + (bn << 8)))[l];   // 256 offsets, 4/lane
  float2 atv = ((const float2*)(attn + (bn << 7)))[l];  // 128 attn, 2/lane

  float acc0 = 0.f, acc1 = 0.f, acc2 = 0.f, acc3 = 0.f;
  const ushort* vbb = value + (((size_t)b * kSTOT) << 8) + (h << 5) + (dq << 2);

  const int lvlW[4] = {80, 40, 20, 10};
  const int lvlH[4] = {64, 32, 16, 8};
  const int lvlO[4] = {0, 5120, 6400, 6720};

#pragma unroll
  for (int p = 0; p < 16; ++p) {
    const int lv = p >> 2;
    const int Wl = lvlW[lv], Hl = lvlH[lv];
    int src = (h << 3) + (p >> 1);
    float ox = __shfl((p & 1) ? ofv.z : ofv.x, src, 64);
    float oy = __shfl((p & 1) ? ofv.w : ofv.y, src, 64);
    float aw = __shfl((p & 1) ? atv.y : atv.x, src, 64);
    float xx = px * (float)Wl + ox - 0.5f;
    float yy = py * (float)Hl + oy - 0.5f;
    float x0f = floorf(xx), y0f = floorf(yy);
    float wx = xx - x0f, wy = yy - y0f;
    int x0 = (int)x0f, y0 = (int)y0f;
    const ushort* vb = vbb + (((size_t)lvlO[lv]) << 8);
    float w00 = (1.f - wx) * (1.f - wy) * aw;
    float w01 = wx * (1.f - wy) * aw;
    float w10 = (1.f - wx) * wy * aw;
    float w11 = wx * wy * aw;
    auto corner = [&](int xi, int yi, float wgt) {
      bool valid = (xi >= 0) && (xi < Wl) && (yi >= 0) && (yi < Hl);
      int xc = xi < 0 ? 0 : (xi > Wl - 1 ? Wl - 1 : xi);
      int yc = yi < 0 ? 0 : (yi > Hl - 1 ? Hl - 1 : yi);
      ushort4 d = *(const ushort4*)(vb + (((size_t)(yc * Wl + xc)) << 8));
      float wg = valid ? wgt : 0.f;
      acc0 = fmaf(wg, bf2f(d.x), acc0);
      acc1 = fmaf(wg, bf2f(d.y), acc1);
      acc2 = fmaf(wg, bf2f(d.z), acc2);
      acc3 = fmaf(wg, bf2f(d.w), acc3);
    };
    corner(x0, y0, w00);
    corner(x0 + 1, y0, w01);
    corner(x0, y0 + 1, w10);
    corner(x0 + 1, y0 + 1, w11);
  }
  *(ushort4*)(samp + (bn << 8) + (h << 5) + (dq << 2)) =
      make_ushort4(f2bf(acc0), f2bf(acc1), f2bf(acc2), f2bf(acc3));
}

// ---------------- concat q_t(fp32)+qloc(fp32) -> qfus bf16 [B*N][512] -------
__global__ void concat_bf_kernel(const float* __restrict__ qt, const float* __restrict__ ql,
                                 ushort* __restrict__ qf) {
  int i = blockIdx.x * 256 + threadIdx.x;
  if (i >= kB * kN * 128) return;
  int c4 = i & 127;
  size_t r = (size_t)(i >> 7);
  float4 v = (c4 < 64) ? ((const float4*)qt)[(r << 6) + c4]
                       : ((const float4*)ql)[(r << 6) + (c4 - 64)];
  ((ushort4*)qf)[i] = make_ushort4(f2bf(v.x), f2bf(v.y), f2bf(v.z), f2bf(v.w));
}

// ---------------- final head: (B*N,256)@(256,7)+b, one wave per row ---------
__global__ void head_kernel(const float* __restrict__ hid, const float* __restrict__ W2,
                            const float* __restrict__ b2, float* __restrict__ outp) {
  int gid = blockIdx.x * 256 + threadIdx.x;
  int wave = gid >> 6;
  int lane = threadIdx.x & 63;
  if (wave >= kB * kN) return;
  const float* hrow = hid + ((size_t)wave << 8);
  float acc[kNCLS];
#pragma unroll
  for (int j = 0; j < kNCLS; ++j) acc[j] = 0.f;
  for (int k = lane; k < kC; k += 64) {
    float hv = hrow[k];
    const float* wr = W2 + k * kNCLS;
#pragma unroll
    for (int j = 0; j < kNCLS; ++j) acc[j] = fmaf(hv, wr[j], acc[j]);
  }
#pragma unroll
  for (int m = 32; m > 0; m >>= 1) {
#pragma unroll
    for (int j = 0; j < kNCLS; ++j) acc[j] += __shfl_xor(acc[j], m);
  }
  float r = 0.f;
#pragma unroll
  for (int j = 0; j < kNCLS; ++j)
    if (lane == j) r = acc[j] + b2[j];
  if (lane < kNCLS) outp[(size_t)wave * kNCLS + lane] = r;
}

}  // namespace

extern "C" void kernel_launch(void* const* d_in, const int* in_sizes, int n_in,
                              void* d_out, int out_size, void* d_ws, size_t ws_size,
                              hipStream_t stream) {
  const float* q_t    = (const float*)d_in[0];
  const float* h_t    = (const float*)d_in[1];
  const float* p_head = (const float*)d_in[2];
  const float* W_off  = (const float*)d_in[3];
  const float* b_off  = (const float*)d_in[4];
  const float* W_attn = (const float*)d_in[5];
  const float* b_attn = (const float*)d_in[6];
  const float* W_v    = (const float*)d_in[7];
  const float* b_v    = (const float*)d_in[8];
  const float* W_o    = (const float*)d_in[9];
  const float* b_o    = (const float*)d_in[10];
  const float* W_p1   = (const float*)d_in[11];
  const float* b_p1   = (const float*)d_in[12];
  const float* W_p2   = (const float*)d_in[13];
  const float* b_p2   = (const float*)d_in[14];
  float* out = (float*)d_out;
  char* wsb = (char*)d_ws;

  // byte offsets (all 256-aligned)
  ushort* fsc   = (ushort*)(wsb + 0);            // 55,705,600 B (bf16 f_scales)
  ushort* value = (ushort*)(wsb + 55705600);     // 55,705,600 B
  ushort* q_bf  = (ushort*)(wsb + 111411200);    //  8,388,608 B
  float*  offb  = (float*)(wsb + 119799808);     // 16,777,216 B
  float*  attn  = (float*)(wsb + 136577024);     //  8,388,608 B
  ushort* samp  = (ushort*)(wsb + 144965632);    //  8,388,608 B
  ushort* wtp   = (ushort*)(wsb + 153354240);    //    720,896 B
  ushort* Wt_v    = wtp;
  ushort* Wt_off  = wtp + 65536;
  ushort* Wt_attn = wtp + 131072;
  ushort* Wt_o    = wtp + 163840;
  ushort* Wt_p1   = wtp + 229376;
  // aliases over fsc (dead after value GEMM):
  float*  qloc = (float*)(wsb + 0);              // 16,777,216 B
  ushort* qfus = (ushort*)(wsb + 16777216);      // 16,777,216 B
  float*  hid  = (float*)(wsb + 33554432);       // 16,777,216 B

  // casts + pyramid
  cast_f2b_kernel<<<4096, 256, 0, stream>>>(q_t, q_bf, kB * kN * 64);
  cast_h_kernel<<<20480, 256, 0, stream>>>(h_t, fsc);
  pool_f2b_kernel<<<20480, 256, 0, stream>>>(h_t, fsc);
  pool_b2b_kernel<<<5120, 256, 0, stream>>>(fsc, fsc, 16, 20, 5120, 6400);
  pool_b2b_kernel<<<1280, 256, 0, stream>>>(fsc, fsc, 8, 10, 6400, 6720);

  // weight transpose+cast
  wtrans_kernel<<<dim3(8, 8), 256, 0, stream>>>(W_v, Wt_v, 256, 256);
  wtrans_kernel<<<dim3(8, 8), 256, 0, stream>>>(W_off, Wt_off, 256, 256);
  wtrans_kernel<<<dim3(4, 8), 256, 0, stream>>>(W_attn, Wt_attn, 256, 128);
  wtrans_kernel<<<dim3(8, 8), 256, 0, stream>>>(W_o, Wt_o, 256, 256);
  wtrans_kernel<<<dim3(8, 16), 256, 0, stream>>>(W_p1, Wt_p1, 512, 256);

  // GEMMs
  gemm_bf16_kernel<256, false, true><<<dim3(2, 850), 256, 0, stream>>>(fsc, Wt_v, b_v, value, 256);
  gemm_bf16_kernel<256, false, false><<<dim3(2, 128), 256, 0, stream>>>(q_bf, Wt_off, b_off, offb, 256);
  gemm_bf16_kernel<256, false, false><<<dim3(1, 128), 256, 0, stream>>>(q_bf, Wt_attn, b_attn, attn, 128);
  softmax16_kernel<<<512, 256, 0, stream>>>(attn, kB * kN * 8);

  // deformable sampling
  deform_kernel<<<4096, 256, 0, stream>>>(value, offb, attn, p_head, samp);

  // tail
  gemm_bf16_kernel<256, false, false><<<dim3(2, 128), 256, 0, stream>>>(samp, Wt_o, b_o, qloc, 256);
  concat_bf_kernel<<<8192, 256, 0, stream>>>(q_t, qloc, qfus);
  gemm_bf16_kernel<512, true, false><<<dim3(2, 128), 256, 0, stream>>>(qfus, Wt_p1, b_p1, hid, 256);
  head_kernel<<<4096, 256, 0, stream>>>(hid, W_p2, b_p2, out);
}